// Round 5
// baseline (100.341 us; speedup 1.0000x reference)
//
#include <hip/hip_runtime.h>

#define M_GT 256

__global__ __launch_bounds__(256) void roi_assign_kernel(
    const float4* __restrict__ proposals,  // [N]
    const float4* __restrict__ gt_boxes,   // [256]
    const int*    __restrict__ gt_labels,  // [256]
    float*        __restrict__ out_labels, // [N]
    float4*       __restrict__ out_deltas, // [N]
    int N)
{
    // Interleaved GT table: slot(g) = ((g&127)<<1) | (g>>7), so that box[k]
    // (read by even lanes) and box[k+128] (read by odd lanes) sit in ADJACENT
    // float4 slots -> lane-pair addresses differ by 16B -> different banks,
    // no 2-way conflict (R4's 5.24M conflict cycles came from the 2048B
    // stride mapping to the same bank).
    __shared__ float4 s_box[M_GT];

    int tid = threadIdx.x;
    float4 g0 = gt_boxes[tid];
    s_box[((tid & 127) << 1) | (tid >> 7)] = g0;
    __syncthreads();

    // lane pair (2k,2k+1) shares one proposal; parity picks the GT half
    int p_local = tid >> 1;
    int part    = tid & 1;
    int i = blockIdx.x * 128 + p_local;
    if (i >= N) return;   // uniform per pair (never taken at our sizes)

    float4 p = proposals[i];
    float areaA = (p.z - p.x) * (p.w - p.y);

    // argmax over t_j = inter_j / S_j  (S = areaA + areaB) — monotone in IoU.
    // Exact rational compare via cross-multiplication. Two independent
    // chains (even/odd local k) for ILP on the select recurrence.
    // Local k in [0,128) maps to global GT index part*128 + k, stored at
    // LDS slot 2k + part.
    float biE = -1.f, bSE = 1.f; int bkE = 0;
    float biO = -1.f, bSO = 1.f; int bkO = 1;

#pragma unroll 4
    for (int m = 0; m < 64; ++m) {          // k = 2m (E), 2m+1 (O)
        float4 gE = s_box[(m << 2) + part];       // slot 4m+part
        float4 gO = s_box[(m << 2) + 2 + part];   // slot 4m+2+part

        {   // even chain — area recomputed in VALU (s_area deleted from LDS)
            float aB = (gE.z - gE.x) * (gE.w - gE.y);
            float lx = fmaxf(p.x, gE.x), ly = fmaxf(p.y, gE.y);
            float rx = fminf(p.z, gE.z), ry = fminf(p.w, gE.w);
            float w = fmaxf(rx - lx, 0.f), h = fmaxf(ry - ly, 0.f);
            float inter = w * h;
            float S = areaA + aB;
            bool upd = (inter * bSE) > (biE * S);
            biE = upd ? inter   : biE;
            bSE = upd ? S       : bSE;
            bkE = upd ? (m << 1) : bkE;
        }
        {   // odd chain
            float aB = (gO.z - gO.x) * (gO.w - gO.y);
            float lx = fmaxf(p.x, gO.x), ly = fmaxf(p.y, gO.y);
            float rx = fminf(p.z, gO.z), ry = fminf(p.w, gO.w);
            float w = fmaxf(rx - lx, 0.f), h = fmaxf(ry - ly, 0.f);
            float inter = w * h;
            float S = areaA + aB;
            bool upd = (inter * bSO) > (biO * S);
            biO = upd ? inter        : biO;
            bSO = upd ? S            : bSO;
            bkO = upd ? (m << 1) + 1 : bkO;
        }
    }

    // merge even/odd chains; tie (equal cross-products) -> smaller k
    float ca = biO * bSE, cb = biE * bSO;
    bool takeO = (ca > cb) || ((ca == cb) && (bkO < bkE));
    float bi = takeO ? biO : biE;
    float bS = takeO ? bSO : bSE;
    int   bk = takeO ? bkO : bkE;
    int   bx = (part << 7) + bk;            // global GT index

    // cross-lane merge between part0 (even lane) and part1 (odd lane);
    // adjacent-lane shfl_xor -> DPP, stays on the VALU pipe.
    float o_bi = __shfl_xor(bi, 1);
    float o_bS = __shfl_xor(bS, 1);
    int   o_bx = __shfl_xor(bx, 1);

    float b0i = part ? o_bi : bi,  b1i = part ? bi : o_bi;
    float b0S = part ? o_bS : bS,  b1S = part ? bS : o_bS;
    int   b0x = part ? o_bx : bx,  b1x = part ? bx : o_bx;

    // strict > : on tie keep part0 (all its indices are smaller)
    bool take1 = (b1i * b0S) > (b0i * b1S);
    float mI = take1 ? b1i : b0i;
    float mS = take1 ? b1S : b0S;
    int   mx = take1 ? b1x : b0x;

    float uni = mS - mI;                   // same rounding as ref's union
    float iou = mI / uni;                  // single IEEE f32 division
    bool pos = (iou >= 0.5f);

    int mslot = ((mx & 127) << 1) | (mx >> 7);   // interleaved slot of box[mx]

    if (part == 0) {
        // even lane: label
        out_labels[i] = pos ? (float)gt_labels[mx] : 0.0f;
    } else {
        // odd lane: box-delta encode
        float4 g = s_box[mslot];
        float pw = p.z - p.x, ph = p.w - p.y;
        float px = p.x + 0.5f * pw, py = p.y + 0.5f * ph;
        float gw = g.z - g.x, gh = g.w - g.y;
        float gx = g.x + 0.5f * gw, gy = g.y + 0.5f * gh;
        float4 d;
        if (pos) {
            d.x = (gx - px) / pw;
            d.y = (gy - py) / ph;
            d.z = logf(gw / pw);
            d.w = logf(gh / ph);
        } else {
            d.x = 0.f; d.y = 0.f; d.z = 0.f; d.w = 0.f;
        }
        out_deltas[i] = d;
    }
}

extern "C" void kernel_launch(void* const* d_in, const int* in_sizes, int n_in,
                              void* d_out, int out_size, void* d_ws, size_t ws_size,
                              hipStream_t stream) {
    const float4* proposals = (const float4*)d_in[0];
    const float4* gt_boxes  = (const float4*)d_in[1];
    const int*    gt_labels = (const int*)d_in[2];

    int N = in_sizes[0] / 4;   // 262144

    float*  out_labels = (float*)d_out;               // first N floats
    float4* out_deltas = (float4*)((float*)d_out + N);

    dim3 block(256);
    dim3 grid((N + 127) / 128);   // 2 threads per proposal
    roi_assign_kernel<<<grid, block, 0, stream>>>(
        proposals, gt_boxes, gt_labels, out_labels, out_deltas, N);
}

// Round 6
// 93.181 us; speedup vs baseline: 1.0769x; 1.0769x over previous
//
#include <hip/hip_runtime.h>

#define M_GT 256

__global__ __launch_bounds__(256, 4) void roi_assign_kernel(
    const float4* __restrict__ proposals,  // [N]
    const float4* __restrict__ gt_boxes,   // [256]
    const int*    __restrict__ gt_labels,  // [256]
    float*        __restrict__ out_labels, // [N]
    float4*       __restrict__ out_deltas, // [N]
    int N)
{
    __shared__ float4 s_box[M_GT];
    __shared__ float  s_area[M_GT];

    int tid = threadIdx.x;
    float4 g0 = gt_boxes[tid];
    s_box[tid]  = g0;
    s_area[tid] = (g0.z - g0.x) * (g0.w - g0.y);
    __syncthreads();

    int i = blockIdx.x * blockDim.x + tid;
    if (i >= N) return;

    float4 p = proposals[i];
    float areaA = (p.z - p.x) * (p.w - p.y);

    // 4 independent best-chains over j % 4 (argmax of t_j = inter_j / S_j,
    // S = areaA + areaB, exact rational compare via cross-multiplication).
    float bi0 = -1.f, bS0 = 1.f; int bk0 = 0;
    float bi1 = -1.f, bS1 = 1.f; int bk1 = 1;
    float bi2 = -1.f, bS2 = 1.f; int bk2 = 2;
    float bi3 = -1.f, bS3 = 1.f; int bk3 = 3;

    const float4* s_area4 = reinterpret_cast<const float4*>(s_area);

#define STEP(g, av, BI, BS, BK, JJ)                                   \
    { float lx = fmaxf(p.x, (g).x), ly = fmaxf(p.y, (g).y);           \
      float rx = fminf(p.z, (g).z), ry = fminf(p.w, (g).w);           \
      float w = fmaxf(rx - lx, 0.f), h = fmaxf(ry - ly, 0.f);         \
      float inter = w * h;                                            \
      float S = areaA + (av);                                         \
      bool upd = (inter * BS) > (BI * S);                             \
      BI = upd ? inter : BI;                                          \
      BS = upd ? S     : BS;                                          \
      BK = upd ? (JJ)  : BK; }

    // register double-buffer: prefetch next batch (4 boxes + area quad)
    // before computing the current one, so LDS latency hides under VALU.
    float4 c0 = s_box[0], c1 = s_box[1], c2 = s_box[2], c3 = s_box[3];
    float4 aq = s_area4[0];

#pragma unroll 2
    for (int m = 0; m < 64; ++m) {
        int nb = (m + 1) & 63;           // last prefetch wraps, unused values
        float4 n0 = s_box[nb * 4 + 0];
        float4 n1 = s_box[nb * 4 + 1];
        float4 n2 = s_box[nb * 4 + 2];
        float4 n3 = s_box[nb * 4 + 3];
        float4 na = s_area4[nb];

        int j = m << 2;
        STEP(c0, aq.x, bi0, bS0, bk0, j)
        STEP(c1, aq.y, bi1, bS1, bk1, j + 1)
        STEP(c2, aq.z, bi2, bS2, bk2, j + 2)
        STEP(c3, aq.w, bi3, bS3, bk3, j + 3)

        c0 = n0; c1 = n1; c2 = n2; c3 = n3; aq = na;
    }
#undef STEP

    // merge 4 chains; exact tie (equal cross-products) -> smaller index,
    // preserving jnp.argmax first-occurrence semantics.
#define MERGE(Ai, AS, Ak, Bi, BS, Bk)                                 \
    { float ca = (Bi) * (AS), cb = (Ai) * (BS);                       \
      bool t = (ca > cb) || ((ca == cb) && ((Bk) < (Ak)));            \
      Ai = t ? (Bi) : (Ai);                                           \
      AS = t ? (BS) : (AS);                                           \
      Ak = t ? (Bk) : (Ak); }

    MERGE(bi0, bS0, bk0, bi1, bS1, bk1)
    MERGE(bi2, bS2, bk2, bi3, bS3, bk3)
    MERGE(bi0, bS0, bk0, bi2, bS2, bk2)
#undef MERGE

    float uni = bS0 - bi0;               // same rounding as ref's union
    float iou = bi0 / uni;               // single IEEE f32 division
    bool pos = (iou >= 0.5f);
    int  mx  = bk0;

    out_labels[i] = pos ? (float)gt_labels[mx] : 0.0f;

    float4 g = s_box[mx];
    float pw = p.z - p.x, ph = p.w - p.y;
    float px = p.x + 0.5f * pw, py = p.y + 0.5f * ph;
    float gw = g.z - g.x, gh = g.w - g.y;
    float gx = g.x + 0.5f * gw, gy = g.y + 0.5f * gh;

    float4 d;
    if (pos) {
        d.x = (gx - px) / pw;
        d.y = (gy - py) / ph;
        d.z = logf(gw / pw);
        d.w = logf(gh / ph);
    } else {
        d.x = 0.f; d.y = 0.f; d.z = 0.f; d.w = 0.f;
    }
    out_deltas[i] = d;
}

extern "C" void kernel_launch(void* const* d_in, const int* in_sizes, int n_in,
                              void* d_out, int out_size, void* d_ws, size_t ws_size,
                              hipStream_t stream) {
    const float4* proposals = (const float4*)d_in[0];
    const float4* gt_boxes  = (const float4*)d_in[1];
    const int*    gt_labels = (const int*)d_in[2];

    int N = in_sizes[0] / 4;   // 262144

    float*  out_labels = (float*)d_out;               // first N floats
    float4* out_deltas = (float4*)((float*)d_out + N);

    dim3 block(256);
    dim3 grid((N + 255) / 256);
    roi_assign_kernel<<<grid, block, 0, stream>>>(
        proposals, gt_boxes, gt_labels, out_labels, out_deltas, N);
}